// Round 8
// baseline (50.863 us; speedup 1.0000x reference)
//
#include <hip/hip_runtime.h>
#include <hip/hip_fp16.h>
#include <stdint.h>

// HashGridEncoder forward (Instant-NGP style), MI355X / gfx950.
// L=16 levels, T=2^15 entries/level, F=2 features, DIM=3.
//
// Structure (round 4): one block per (level, point-chunk); level's 32768-entry
// table slice staged in LDS as packed f16x2 (128KB), all gathers are LDS.
// bid = l*16 + c -> XCD = c%8: the 16 level-blocks of a chunk share an XCD so
// partial 8B writes per 128B out-line merge in L2 (WRITE_SIZE = 62.5MB).
//
// Round-8: occupancy is LDS-capped at 16 waves/CU regardless of VGPR, so
// spend registers on ILP: 4-point groups -> 32 outstanding ds_read_b32 per
// wave (512 per CU), fenced issue block, then x-prefetch + 4 consume/store
// blocks drained by the compiler's counted lgkmcnt. Rounds 5-7 showed all
// pipes <=35% busy at 2-point depth -> pure latency shortfall.
// Falsifier: VGPR must rise to ~90-115; flat dur at high VGPR => per-wave
// LDS return-queue limit -> pivot structure next round.

constexpr int      kL  = 16;
constexpr int      kT  = 32768;           // 2^15
constexpr uint32_t kM  = kT - 1;
constexpr uint32_t kP1 = 2654435761u;
constexpr uint32_t kP2 = 805459861u;
constexpr int      kNC = 16;              // point chunks (multiple of 8)
constexpr int      kBT = 1024;            // threads per block
constexpr int      kG  = 4;               // points per thread per group

typedef float f32x2 __attribute__((ext_vector_type(2)));

// scales[l] = 16 * 2^(l/3) - 1  (B = 2^(1/3) exactly), f64-rounded to f32.
__device__ __constant__ float c_scales[kL] = {
    15.0f,
    19.158736798317972f,
    24.398416831491190f,
    31.0f,
    39.317473596635944f,
    49.796833662982380f,
    63.0f,
    79.634947193271890f,
    100.59366732596477f,
    127.0f,
    160.26989438654378f,
    202.18733465192953f,
    255.0f,
    321.53978877308750f,
    405.37466930385903f,
    511.0f
};

__device__ __forceinline__ void load3(float (&v)[3], const float* __restrict__ x, int n) {
    v[0] = x[n * 3 + 0];
    v[1] = x[n * 3 + 1];
    v[2] = x[n * 3 + 2];
}

// hash the point and ISSUE the 8 LDS reads; only fr[] is kept for weights.
__device__ __forceinline__ void hash_issue(
    const uint32_t* __restrict__ ltab, float s, const float (&xv)[3],
    float (&fr)[3], uint32_t (&buf)[8])
{
    float p0 = fmaf((xv[0] + 1.0f) * 0.5f, s, 0.5f);
    float p1 = fmaf((xv[1] + 1.0f) * 0.5f, s, 0.5f);
    float p2 = fmaf((xv[2] + 1.0f) * 0.5f, s, 0.5f);

    float fl0 = floorf(p0), fl1 = floorf(p1), fl2 = floorf(p2);
    fr[0] = p0 - fl0;  fr[1] = p1 - fl1;  fr[2] = p2 - fl2;

    uint32_t g0 = (uint32_t)(int)fl0;
    uint32_t g1 = (uint32_t)(int)fl1;
    uint32_t g2 = (uint32_t)(int)fl2;

    uint32_t g0p = g0 + 1u;
    uint32_t hy0 = g1 * kP1;  uint32_t hy1 = hy0 + kP1;
    uint32_t hz0 = g2 * kP2;  uint32_t hz1 = hz0 + kP2;

    uint32_t hyz0 = hy0 ^ hz0;
    uint32_t hyz1 = hy1 ^ hz0;
    uint32_t hyz2 = hy0 ^ hz1;
    uint32_t hyz3 = hy1 ^ hz1;

    buf[0] = ltab[(g0  ^ hyz0) & kM];
    buf[1] = ltab[(g0p ^ hyz0) & kM];
    buf[2] = ltab[(g0  ^ hyz1) & kM];
    buf[3] = ltab[(g0p ^ hyz1) & kM];
    buf[4] = ltab[(g0  ^ hyz2) & kM];
    buf[5] = ltab[(g0p ^ hyz2) & kM];
    buf[6] = ltab[(g0  ^ hyz3) & kM];
    buf[7] = ltab[(g0p ^ hyz3) & kM];
}

// weight math (independent of the loads) + consume.
__device__ __forceinline__ f32x2 wconsume(const float (&fr)[3], const uint32_t (&buf)[8]) {
    float wx0 = 1.0f - fr[0];
    float wy0 = 1.0f - fr[1];
    float wz0 = 1.0f - fr[2];
    float wyz0 = wy0   * wz0;
    float wyz1 = fr[1] * wz0;
    float wyz2 = wy0   * fr[2];
    float wyz3 = fr[1] * fr[2];

    float wf[8];
    wf[0] = wx0   * wyz0;  wf[1] = fr[0] * wyz0;
    wf[2] = wx0   * wyz1;  wf[3] = fr[0] * wyz1;
    wf[4] = wx0   * wyz2;  wf[5] = fr[0] * wyz2;
    wf[6] = wx0   * wyz3;  wf[7] = fr[0] * wyz3;

    __half2 acc = __float2half2_rn(0.0f);
#pragma unroll
    for (int cc = 0; cc < 8; ++cc) {
        __half2 h = *reinterpret_cast<const __half2*>(&buf[cc]);
        acc = __hfma2(__float2half2_rn(wf[cc]), h, acc);
    }
    f32x2 r;
    r.x = __low2float(acc);
    r.y = __high2float(acc);
    return r;
}

__global__ __launch_bounds__(kBT, 4) void hashgrid_fwd(
    const float*  __restrict__ x,      // (N,3)
    const float2* __restrict__ table,  // (L,T) of float2
    f32x2*        __restrict__ out,    // (N,L) of float2
    int n_points, int chunk_sz)
{
    __shared__ uint32_t ltab[kT];      // 128 KB: level slice as packed f16x2

    int bid = blockIdx.x;
    int l   = bid >> 4;                // bid = l*16 + c  -> XCD = c%8
    int c   = bid & 15;

    // ---- stage level slice: 32768 f32x2 -> packed f16x2 (float4 loads) ----
    const float4* tsrc4 = reinterpret_cast<const float4*>(table + (size_t)l * kT);
    for (int e = threadIdx.x; e < kT / 2; e += kBT) {
        float4 q = tsrc4[e];
        uint2 pp;
        pp.x = ((uint32_t)__half_as_ushort(__float2half_rn(q.y)) << 16)
             |  (uint32_t)__half_as_ushort(__float2half_rn(q.x));
        pp.y = ((uint32_t)__half_as_ushort(__float2half_rn(q.w)) << 16)
             |  (uint32_t)__half_as_ushort(__float2half_rn(q.z));
        *reinterpret_cast<uint2*>(&ltab[e * 2]) = pp;
    }
    __syncthreads();

    float s    = c_scales[l];
    int   tid  = (int)threadIdx.x;
    int   base = c * chunk_sz;
    int   lim  = min(base + chunk_sz, n_points);

    // main iterations with NO bounds checks: it in [0, unguarded)
    int unguarded = (chunk_sz / kBT) & ~(kG - 1);  // 28 for chunk_sz=31250

    int n = base + tid;
    float xc[kG][3];
#pragma unroll
    for (int p = 0; p < kG; ++p) load3(xc[p], x, n + p * kBT);

    for (int it = 0; it < unguarded; it += kG) {
        float    fr[kG][3];
        uint32_t b[kG][8];

        // ---- phase 1: hash + issue all 32 LDS reads ----
#pragma unroll
        for (int p = 0; p < kG; ++p)
            hash_issue(ltab, s, xc[p], fr[p], b[p]);
        __builtin_amdgcn_sched_barrier(0);

        // ---- phase 2: x prefetch for next group (covers LDS+HBM latency) ----
        bool last = (it + kG >= unguarded);
#pragma unroll
        for (int p = 0; p < kG; ++p) {
            int np = last ? n : n + (kG + p) * kBT;   // in-chunk, always valid
            load3(xc[p], x, np);
        }

        // ---- phase 3: weights + consume (counted lgkmcnt) + store ----
#pragma unroll
        for (int p = 0; p < kG; ++p) {
            f32x2 r = wconsume(fr[p], b[p]);
            out[(size_t)(n + p * kBT) * kL + l] = r;
        }

        n += kG * kBT;
    }

    // guarded tail (3 iterations for chunk_sz=31250)
    for (int nG = base + tid + unguarded * kBT; nG < lim; nG += kBT) {
        float xv[3];
        load3(xv, x, nG);
        float frv[3]; uint32_t bv[8];
        hash_issue(ltab, s, xv, frv, bv);
        f32x2 r = wconsume(frv, bv);
        out[(size_t)nG * kL + l] = r;
    }
}

extern "C" void kernel_launch(void* const* d_in, const int* in_sizes, int n_in,
                              void* d_out, int out_size, void* d_ws, size_t ws_size,
                              hipStream_t stream) {
    const float*  x     = (const float*)d_in[0];
    const float2* table = (const float2*)d_in[1];
    f32x2*        out   = (f32x2*)d_out;

    int n_points = in_sizes[0] / 3;                  // (N,3) flat
    int chunk_sz = (n_points + kNC - 1) / kNC;       // 31250 for N=500000
    int blocks   = kL * kNC;                         // 256 = 1 per CU

    hashgrid_fwd<<<blocks, kBT, 0, stream>>>(x, table, out, n_points, chunk_sz);
}

// Round 9
// 50.135 us; speedup vs baseline: 1.0145x; 1.0145x over previous
//
#include <hip/hip_runtime.h>
#include <hip/hip_fp16.h>
#include <stdint.h>

// HashGridEncoder forward (Instant-NGP style), MI355X / gfx950.
// L=16 levels, T=2^15 entries/level, F=2 features, DIM=3.
//
// Structure (round 4): one block per (level, point-chunk); level's 32768-entry
// table slice staged in LDS as packed f16x2 (128KB), all gathers are LDS.
// bid = l*16 + c -> XCD = c%8: the 16 level-blocks of a chunk share an XCD so
// partial 8B writes per 128B out-line merge in L2 (WRITE_SIZE = 62.5MB).
//
// Round-9: rounds 5-8 proved the compiler sinks C-level LDS loads to their
// uses no matter the source structure (VGPR pinned at 52; measured
// 983 cyc/item = 8 serialized LDS round-trips). Fix per m214 ladder:
// INLINE-ASM ds_read_b32 (unmovable issue point), 16 reads in flight per
// 2-point group, explicit s_waitcnt lgkmcnt(0) + sched_barrier(0) before
// consume (rule #18), early-clobber outputs (register aliasing). Falsifier:
// VGPR must rise to ~70-90.

constexpr int      kL  = 16;
constexpr int      kT  = 32768;           // 2^15
constexpr uint32_t kM  = kT - 1;
constexpr uint32_t kP1 = 2654435761u;
constexpr uint32_t kP2 = 805459861u;
constexpr int      kNC = 16;              // point chunks (multiple of 8)
constexpr int      kBT = 1024;            // threads per block

typedef float f32x2 __attribute__((ext_vector_type(2)));
typedef __attribute__((address_space(3))) uint32_t u32_lds;

// scales[l] = 16 * 2^(l/3) - 1  (B = 2^(1/3) exactly), f64-rounded to f32.
__device__ __constant__ float c_scales[kL] = {
    15.0f,
    19.158736798317972f,
    24.398416831491190f,
    31.0f,
    39.317473596635944f,
    49.796833662982380f,
    63.0f,
    79.634947193271890f,
    100.59366732596477f,
    127.0f,
    160.26989438654378f,
    202.18733465192953f,
    255.0f,
    321.53978877308750f,
    405.37466930385903f,
    511.0f
};

__device__ __forceinline__ void load3(float (&v)[3], const float* __restrict__ x, int n) {
    v[0] = x[n * 3 + 0];
    v[1] = x[n * 3 + 1];
    v[2] = x[n * 3 + 2];
}

// hash the point: keep fr[] for weights, compute the 8 LDS BYTE ADDRESSES.
__device__ __forceinline__ void hash_addr(
    uint32_t lbase, float s, const float (&xv)[3],
    float (&fr)[3], uint32_t (&adr)[8])
{
    float p0 = fmaf((xv[0] + 1.0f) * 0.5f, s, 0.5f);
    float p1 = fmaf((xv[1] + 1.0f) * 0.5f, s, 0.5f);
    float p2 = fmaf((xv[2] + 1.0f) * 0.5f, s, 0.5f);

    float fl0 = floorf(p0), fl1 = floorf(p1), fl2 = floorf(p2);
    fr[0] = p0 - fl0;  fr[1] = p1 - fl1;  fr[2] = p2 - fl2;

    uint32_t g0 = (uint32_t)(int)fl0;
    uint32_t g1 = (uint32_t)(int)fl1;
    uint32_t g2 = (uint32_t)(int)fl2;

    uint32_t g0p = g0 + 1u;
    uint32_t hy0 = g1 * kP1;  uint32_t hy1 = hy0 + kP1;
    uint32_t hz0 = g2 * kP2;  uint32_t hz1 = hz0 + kP2;

    uint32_t hyz0 = hy0 ^ hz0;
    uint32_t hyz1 = hy1 ^ hz0;
    uint32_t hyz2 = hy0 ^ hz1;
    uint32_t hyz3 = hy1 ^ hz1;

    adr[0] = lbase + (((g0  ^ hyz0) & kM) << 2);
    adr[1] = lbase + (((g0p ^ hyz0) & kM) << 2);
    adr[2] = lbase + (((g0  ^ hyz1) & kM) << 2);
    adr[3] = lbase + (((g0p ^ hyz1) & kM) << 2);
    adr[4] = lbase + (((g0  ^ hyz2) & kM) << 2);
    adr[5] = lbase + (((g0p ^ hyz2) & kM) << 2);
    adr[6] = lbase + (((g0  ^ hyz3) & kM) << 2);
    adr[7] = lbase + (((g0p ^ hyz3) & kM) << 2);
}

// ISSUE 8 ds_read_b32 via inline asm — unmovable, stays in flight.
__device__ __forceinline__ void issue_asm8(const uint32_t (&adr)[8], uint32_t (&e)[8]) {
    asm volatile(
        "ds_read_b32 %0, %8\n\t"
        "ds_read_b32 %1, %9\n\t"
        "ds_read_b32 %2, %10\n\t"
        "ds_read_b32 %3, %11\n\t"
        "ds_read_b32 %4, %12\n\t"
        "ds_read_b32 %5, %13\n\t"
        "ds_read_b32 %6, %14\n\t"
        "ds_read_b32 %7, %15"
        : "=&v"(e[0]), "=&v"(e[1]), "=&v"(e[2]), "=&v"(e[3]),
          "=&v"(e[4]), "=&v"(e[5]), "=&v"(e[6]), "=&v"(e[7])
        : "v"(adr[0]), "v"(adr[1]), "v"(adr[2]), "v"(adr[3]),
          "v"(adr[4]), "v"(adr[5]), "v"(adr[6]), "v"(adr[7]));
}

// weight math (independent of loads) — f32 corner weights.
__device__ __forceinline__ void weights8(const float (&fr)[3], float (&wf)[8]) {
    float wx0 = 1.0f - fr[0];
    float wy0 = 1.0f - fr[1];
    float wz0 = 1.0f - fr[2];
    float wyz0 = wy0   * wz0;
    float wyz1 = fr[1] * wz0;
    float wyz2 = wy0   * fr[2];
    float wyz3 = fr[1] * fr[2];
    wf[0] = wx0   * wyz0;  wf[1] = fr[0] * wyz0;
    wf[2] = wx0   * wyz1;  wf[3] = fr[0] * wyz1;
    wf[4] = wx0   * wyz2;  wf[5] = fr[0] * wyz2;
    wf[6] = wx0   * wyz3;  wf[7] = fr[0] * wyz3;
}

__device__ __forceinline__ f32x2 consume8(const uint32_t (&e)[8], const float (&wf)[8]) {
    __half2 acc = __float2half2_rn(0.0f);
#pragma unroll
    for (int cc = 0; cc < 8; ++cc) {
        __half2 h = *reinterpret_cast<const __half2*>(&e[cc]);
        acc = __hfma2(__float2half2_rn(wf[cc]), h, acc);
    }
    f32x2 r;
    r.x = __low2float(acc);
    r.y = __high2float(acc);
    return r;
}

__global__ __launch_bounds__(kBT, 4) void hashgrid_fwd(
    const float*  __restrict__ x,      // (N,3)
    const float2* __restrict__ table,  // (L,T) of float2
    f32x2*        __restrict__ out,    // (N,L) of float2
    int n_points, int chunk_sz)
{
    __shared__ uint32_t ltab[kT];      // 128 KB: level slice as packed f16x2

    int bid = blockIdx.x;
    int l   = bid >> 4;                // bid = l*16 + c  -> XCD = c%8
    int c   = bid & 15;

    // ---- stage level slice: 32768 f32x2 -> packed f16x2 (float4 loads) ----
    const float4* tsrc4 = reinterpret_cast<const float4*>(table + (size_t)l * kT);
    for (int e = threadIdx.x; e < kT / 2; e += kBT) {
        float4 q = tsrc4[e];
        uint2 pp;
        pp.x = ((uint32_t)__half_as_ushort(__float2half_rn(q.y)) << 16)
             |  (uint32_t)__half_as_ushort(__float2half_rn(q.x));
        pp.y = ((uint32_t)__half_as_ushort(__float2half_rn(q.w)) << 16)
             |  (uint32_t)__half_as_ushort(__float2half_rn(q.z));
        *reinterpret_cast<uint2*>(&ltab[e * 2]) = pp;
    }
    __syncthreads();

    // LDS byte offset of ltab (AS(3) cast -> 32-bit LDS address; CK pattern)
    uint32_t lbase = (uint32_t)(uintptr_t)(u32_lds*)ltab;

    float s    = c_scales[l];
    int   tid  = (int)threadIdx.x;
    int   base = c * chunk_sz;
    int   lim  = min(base + chunk_sz, n_points);

    int unguarded = (chunk_sz / kBT) & ~1;        // 30 for chunk_sz=31250

    int n = base + tid;
    float xc0[3], xc1[3];
    load3(xc0, x, n);
    load3(xc1, x, n + kBT);

    for (int it = 0; it < unguarded; it += 2) {
        float    fr0[3], fr1[3];
        uint32_t a0[8], a1[8];
        uint32_t e0[8], e1[8];

        // ---- phase 1: hash + ISSUE all 16 LDS reads (asm, unmovable) ----
        hash_addr(lbase, s, xc0, fr0, a0);
        hash_addr(lbase, s, xc1, fr1, a1);
        issue_asm8(a0, e0);
        issue_asm8(a1, e1);
        __builtin_amdgcn_sched_barrier(0);

        // ---- phase 2: weight math + x prefetch (covers LDS latency) ----
        float wf0[8], wf1[8];
        weights8(fr0, wf0);
        weights8(fr1, wf1);
        bool last = (it + 2 >= unguarded);
        int  np0  = last ? n : n + 2 * kBT;       // in-chunk, always valid
        int  np1  = last ? n : n + 3 * kBT;
        load3(xc0, x, np0);
        load3(xc1, x, np1);

        // ---- phase 3: drain + consume + store ----
        asm volatile("s_waitcnt lgkmcnt(0)" ::: "memory");
        __builtin_amdgcn_sched_barrier(0);
        f32x2 r0 = consume8(e0, wf0);
        out[(size_t)n * kL + l] = r0;
        f32x2 r1 = consume8(e1, wf1);
        out[(size_t)(n + kBT) * kL + l] = r1;

        n += 2 * kBT;
    }

    // guarded tail (1 iteration for chunk_sz=31250)
    for (int nG = base + tid + unguarded * kBT; nG < lim; nG += kBT) {
        float xv[3];
        load3(xv, x, nG);
        float frv[3]; uint32_t av[8], ev[8];
        hash_addr(lbase, s, xv, frv, av);
        issue_asm8(av, ev);
        float wfv[8];
        weights8(frv, wfv);
        asm volatile("s_waitcnt lgkmcnt(0)" ::: "memory");
        __builtin_amdgcn_sched_barrier(0);
        f32x2 r = consume8(ev, wfv);
        out[(size_t)nG * kL + l] = r;
    }
}

extern "C" void kernel_launch(void* const* d_in, const int* in_sizes, int n_in,
                              void* d_out, int out_size, void* d_ws, size_t ws_size,
                              hipStream_t stream) {
    const float*  x     = (const float*)d_in[0];
    const float2* table = (const float2*)d_in[1];
    f32x2*        out   = (f32x2*)d_out;

    int n_points = in_sizes[0] / 3;                  // (N,3) flat
    int chunk_sz = (n_points + kNC - 1) / kNC;       // 31250 for N=500000
    int blocks   = kL * kNC;                         // 256 = 1 per CU

    hashgrid_fwd<<<blocks, kBT, 0, stream>>>(x, table, out, n_points, chunk_sz);
}